// Round 1
// baseline (346.935 us; speedup 1.0000x reference)
//
#include <hip/hip_runtime.h>
#include <hip/hip_bf16.h>
#include <stdint.h>

#define BATCH   16384
#define EXPERTS 8
#define IN_DIM  1024
#define OUT_DIM 1024

typedef unsigned short u16;
typedef short  bf16x8 __attribute__((ext_vector_type(8)));
typedef float  f32x4  __attribute__((ext_vector_type(4)));

__device__ __forceinline__ u16 f2bf(float f) {
  uint32_t u = __float_as_uint(f);
  u += 0x7fffu + ((u >> 16) & 1u);   // round-to-nearest-even
  return (u16)(u >> 16);
}

// async global->LDS, 16B per lane, wave-uniform LDS base + lane*16
#define GLDS16(g, l)                                                      \
  __builtin_amdgcn_global_load_lds(                                       \
      (const __attribute__((address_space(1))) void*)(g),                 \
      (__attribute__((address_space(3))) void*)(l), 16, 0, 0)

// ---------------- kernel 1: x fp32 -> bf16 ----------------
__global__ void cvt_x(const float* __restrict__ x, u16* __restrict__ xb) {
  size_t i = ((size_t)blockIdx.x * 256 + threadIdx.x) * 4;
  float4 v = *reinterpret_cast<const float4*>(x + i);
  ushort4 o;
  o.x = f2bf(v.x); o.y = f2bf(v.y); o.z = f2bf(v.z); o.w = f2bf(v.w);
  *reinterpret_cast<ushort4*>(xb + i) = o;
}

// ------- kernel 2: W[e][i][o] fp32 -> Wbt[e][o][i] bf16 (transpose) -------
__global__ void cvt_w(const float* __restrict__ W, u16* __restrict__ wbt) {
  __shared__ u16 t[64][72];            // +8 pad
  const int e  = blockIdx.z;
  const int i0 = blockIdx.x * 64;
  const int o0 = blockIdx.y * 64;
  const int tid = threadIdx.x;
  const int c  = (tid & 15) * 4;
  const int r_ = tid >> 4;
  const float* src = W + ((size_t)e << 20);
#pragma unroll
  for (int p = 0; p < 4; ++p) {
    int r = r_ + p * 16;               // i-row
    float4 v = *reinterpret_cast<const float4*>(src + (size_t)(i0 + r) * 1024 + o0 + c);
    t[r][c + 0] = f2bf(v.x); t[r][c + 1] = f2bf(v.y);
    t[r][c + 2] = f2bf(v.z); t[r][c + 3] = f2bf(v.w);
  }
  __syncthreads();
  u16* dst = wbt + ((size_t)e << 20);
#pragma unroll
  for (int p = 0; p < 4; ++p) {
    int orow = r_ + p * 16;            // o-row
    ushort4 u;
    u.x = t[c + 0][orow]; u.y = t[c + 1][orow];
    u.z = t[c + 2][orow]; u.w = t[c + 3][orow];
    *reinterpret_cast<ushort4*>(dst + (size_t)(o0 + orow) * 1024 + i0 + c) = u;
  }
}

// ---------------- kernel 3: the fused expert GEMM ----------------
// C[b,o] = sum_e w[b,e] * (xb[b,:] @ Wbt[e][o,:]) + sum_e w[b,e]*bias[e,o]
// BM=128 BN=64 BK=64, 256 threads = 4 waves, wave -> 32x64 output.
// LDS tiles A[128][64], B[64][64] bf16, XOR-swizzle byte^=((row&7)<<4),
// applied on the global SOURCE (linear global_load_lds dest) and on reads.
__global__ __launch_bounds__(256, 4)
void moe_gemm(const u16* __restrict__ xb, const u16* __restrict__ wbt,
              const float* __restrict__ wts, const float* __restrict__ bias,
              float* __restrict__ y) {
  __shared__ u16 As[128 * 64];
  __shared__ u16 Bs[64 * 64];

  const int tid = threadIdx.x;
  const int l   = tid & 63;
  const int w   = tid >> 6;
  const int b0  = blockIdx.x * 128;
  const int n0  = blockIdx.y * 64;

  // staging: lane covers LDS elems [w*512 + q*2048 + l*8, +8)
  //  -> row = w*8 + q*32 + (l>>3), k-chunk swizzled by ((row&7)<<3) elems
  const int rbase = (w << 3) + (l >> 3);                  // 0..31
  const int kswz  = ((l & 7) ^ (l >> 3)) << 3;            // element offset
  const u16* pA0 = xb  + (size_t)(b0 + rbase) * IN_DIM + kswz;
  const u16* pB0 = wbt + (size_t)(n0 + rbase) * IN_DIM + kswz;
  u16* ldsA = As + (w << 9);
  u16* ldsB = Bs + (w << 9);

  // fragment read byte-offsets (A: row=wave*32+mf*16+(l&15); k=(l>>4)*8 elems)
  int aoff[2][2], boff[4][2];
#pragma unroll
  for (int mf = 0; mf < 2; ++mf) {
    const int r = (w << 5) + (mf << 4) + (l & 15);
    const int m = (r & 7) << 4;
#pragma unroll
    for (int kf = 0; kf < 2; ++kf)
      aoff[mf][kf] = (r << 7) + (((kf << 6) + ((l >> 4) << 4)) ^ m);
  }
#pragma unroll
  for (int nf = 0; nf < 4; ++nf) {
    const int r = (nf << 4) + (l & 15);
    const int m = (r & 7) << 4;
#pragma unroll
    for (int kf = 0; kf < 2; ++kf)
      boff[nf][kf] = (r << 7) + (((kf << 6) + ((l >> 4) << 4)) ^ m);
  }

  f32x4 accY[2][4], accE[2][4];
#pragma unroll
  for (int mf = 0; mf < 2; ++mf)
#pragma unroll
    for (int nf = 0; nf < 4; ++nf) {
      accY[mf][nf] = (f32x4){0.f, 0.f, 0.f, 0.f};
      accE[mf][nf] = (f32x4){0.f, 0.f, 0.f, 0.f};
    }

  const char* Asb = (const char*)As;
  const char* Bsb = (const char*)Bs;

  for (int e = 0; e < EXPERTS; ++e) {
    const u16* pA = pA0;
    const u16* pB = pB0 + (size_t)e * IN_DIM * 1024;
    for (int kk = 0; kk < 16; ++kk) {
      const int koff = kk << 6;
      GLDS16(pA + koff,                 ldsA);
      GLDS16(pA + koff + 32 * IN_DIM,   ldsA + 2048);
      GLDS16(pA + koff + 64 * IN_DIM,   ldsA + 4096);
      GLDS16(pA + koff + 96 * IN_DIM,   ldsA + 6144);
      GLDS16(pB + koff,                 ldsB);
      GLDS16(pB + koff + 32 * IN_DIM,   ldsB + 2048);
      __syncthreads();                  // drains vmcnt before barrier
#pragma unroll
      for (int kf = 0; kf < 2; ++kf) {
        bf16x8 af[2], bfr[4];
#pragma unroll
        for (int mf = 0; mf < 2; ++mf)
          af[mf] = *(const bf16x8*)(Asb + aoff[mf][kf]);
#pragma unroll
        for (int nf = 0; nf < 4; ++nf)
          bfr[nf] = *(const bf16x8*)(Bsb + boff[nf][kf]);
#pragma unroll
        for (int mf = 0; mf < 2; ++mf)
#pragma unroll
          for (int nf = 0; nf < 4; ++nf)
            accE[mf][nf] = __builtin_amdgcn_mfma_f32_16x16x32_bf16(
                af[mf], bfr[nf], accE[mf][nf], 0, 0, 0);
      }
      __syncthreads();
    }
    // fold expert segment: accY += w[b,e] * accE ; accE = 0
#pragma unroll
    for (int mf = 0; mf < 2; ++mf) {
      const int r0 = b0 + (w << 5) + (mf << 4) + ((l >> 4) << 2);
#pragma unroll
      for (int j = 0; j < 4; ++j) {
        const float we = wts[(size_t)(r0 + j) * EXPERTS + e];
#pragma unroll
        for (int nf = 0; nf < 4; ++nf) {
          accY[mf][nf][j] += we * accE[mf][nf][j];
          accE[mf][nf][j] = 0.f;
        }
      }
    }
  }

  // epilogue: add bias term and store fp32
#pragma unroll
  for (int mf = 0; mf < 2; ++mf) {
    const int r0 = b0 + (w << 5) + (mf << 4) + ((l >> 4) << 2);
#pragma unroll
    for (int j = 0; j < 4; ++j) {
      const int r = r0 + j;
      const float* wr = wts + (size_t)r * EXPERTS;
      float w8[8];
#pragma unroll
      for (int e2 = 0; e2 < 8; ++e2) w8[e2] = wr[e2];
#pragma unroll
      for (int nf = 0; nf < 4; ++nf) {
        const int c = n0 + (nf << 4) + (l & 15);
        float v = accY[mf][nf][j];
#pragma unroll
        for (int e2 = 0; e2 < 8; ++e2)
          v += w8[e2] * bias[e2 * OUT_DIM + c];
        y[(size_t)r * OUT_DIM + c] = v;
      }
    }
  }
}

extern "C" void kernel_launch(void* const* d_in, const int* in_sizes, int n_in,
                              void* d_out, int out_size, void* d_ws, size_t ws_size,
                              hipStream_t stream) {
  const float* x    = (const float*)d_in[0];
  const float* wts  = (const float*)d_in[1];
  const float* W    = (const float*)d_in[2];
  const float* bias = (const float*)d_in[3];
  float* y = (float*)d_out;

  const size_t xb_elems = (size_t)BATCH * IN_DIM;                 // 32 MB bf16
  const size_t wb_elems = (size_t)EXPERTS * IN_DIM * OUT_DIM;     // 16 MB bf16
  if (ws_size < (xb_elems + wb_elems) * sizeof(u16)) return;      // loud failure
  u16* xb  = (u16*)d_ws;
  u16* wbt = xb + xb_elems;

  cvt_x<<<(BATCH * IN_DIM) / (4 * 256), 256, 0, stream>>>(x, xb);
  cvt_w<<<dim3(IN_DIM / 64, OUT_DIM / 64, EXPERTS), 256, 0, stream>>>(W, wbt);
  moe_gemm<<<dim3(BATCH / 128, OUT_DIM / 64), 256, 0, stream>>>(xb, wbt, wts, bias, y);
}

// Round 2
// 337.393 us; speedup vs baseline: 1.0283x; 1.0283x over previous
//
#include <hip/hip_runtime.h>
#include <hip/hip_bf16.h>
#include <stdint.h>

#define BATCH   16384
#define EXPERTS 8
#define IN_DIM  1024
#define OUT_DIM 1024

typedef unsigned short u16;
typedef short  bf16x8 __attribute__((ext_vector_type(8)));
typedef float  f32x4  __attribute__((ext_vector_type(4)));

__device__ __forceinline__ u16 f2bf(float f) {
  uint32_t u = __float_as_uint(f);
  u += 0x7fffu + ((u >> 16) & 1u);   // round-to-nearest-even
  return (u16)(u >> 16);
}

// async global->LDS, 16B per lane, wave-uniform LDS base + lane*16
#define GLDS16(g, l)                                                      \
  __builtin_amdgcn_global_load_lds(                                       \
      (const __attribute__((address_space(1))) void*)(g),                 \
      (__attribute__((address_space(3))) void*)(l), 16, 0, 0)

#define MFMA_BF16 __builtin_amdgcn_mfma_f32_16x16x32_bf16

// ---------------- kernel 1: x fp32 -> bf16 ----------------
__global__ void cvt_x(const float* __restrict__ x, u16* __restrict__ xb) {
  size_t i = ((size_t)blockIdx.x * 256 + threadIdx.x) * 4;
  float4 v = *reinterpret_cast<const float4*>(x + i);
  ushort4 o;
  o.x = f2bf(v.x); o.y = f2bf(v.y); o.z = f2bf(v.z); o.w = f2bf(v.w);
  *reinterpret_cast<ushort4*>(xb + i) = o;
}

// ------- kernel 2: W[e][i][o] fp32 -> Wbt[e][o][i] bf16 (transpose) -------
__global__ void cvt_w(const float* __restrict__ W, u16* __restrict__ wbt) {
  __shared__ u16 t[64][72];            // +8 pad
  const int e  = blockIdx.z;
  const int i0 = blockIdx.x * 64;
  const int o0 = blockIdx.y * 64;
  const int tid = threadIdx.x;
  const int c  = (tid & 15) * 4;
  const int r_ = tid >> 4;
  const float* src = W + ((size_t)e << 20);
#pragma unroll
  for (int p = 0; p < 4; ++p) {
    int r = r_ + p * 16;               // i-row
    float4 v = *reinterpret_cast<const float4*>(src + (size_t)(i0 + r) * 1024 + o0 + c);
    t[r][c + 0] = f2bf(v.x); t[r][c + 1] = f2bf(v.y);
    t[r][c + 2] = f2bf(v.z); t[r][c + 3] = f2bf(v.w);
  }
  __syncthreads();
  u16* dst = wbt + ((size_t)e << 20);
#pragma unroll
  for (int p = 0; p < 4; ++p) {
    int orow = r_ + p * 16;            // o-row
    ushort4 u;
    u.x = t[c + 0][orow]; u.y = t[c + 1][orow];
    u.z = t[c + 2][orow]; u.w = t[c + 3][orow];
    *reinterpret_cast<ushort4*>(dst + (size_t)(o0 + orow) * 1024 + i0 + c) = u;
  }
}

// ---------------- kernel 3: fused expert GEMM, 2-phase pipelined ----------
// BM=256 BN=128 BK=64, 512 threads = 8 waves (2M x 4N), wave -> 128x32 out.
// Triple-buffered LDS, prefetch distance 2, counted vmcnt(6) (T3+T4),
// setprio around MFMA clusters (T5), XOR-swizzled LDS (T2, both-sides via
// pre-swizzled global source), per-expert fold via LDS-cached weights.
//
// LDS map (u16 elems): buf k at k*24576 { A: 16384 elems (256x64),
// B: +16384: 8192 elems (128x64) }, wl (f32[8][256]) at elem 73728.
__global__ __launch_bounds__(512, 2)
void moe_gemm(const u16* __restrict__ xb, const u16* __restrict__ wbt,
              const float* __restrict__ wts, const float* __restrict__ bias,
              float* __restrict__ y) {
  __shared__ u16 sm[73728 + 4096];     // 144KB bufs + 8KB weights = 152KB
  float* wl = (float*)(sm + 73728);

  const int tid = threadIdx.x;
  const int l   = tid & 63;
  const int w   = tid >> 6;            // wave 0..7
  const int wm  = w >> 2;              // 0..1
  const int wn  = w & 3;               // 0..3
  const int n0  = (blockIdx.x & 7) * 128;   // XCD-affine: each XCD owns one B-panel
  const int b0  = (blockIdx.x >> 3) * 256;

  // ---- stage expert weights for this block's 256 rows into LDS: wl[e][256]
#pragma unroll
  for (int i = 0; i < 4; ++i) {
    const int flat = tid + i * 512;
    const int ee = flat & 7, r = flat >> 3;
    wl[ee * 256 + r] = wts[(size_t)(b0 + r) * EXPERTS + ee];
  }
  __builtin_amdgcn_sched_barrier(0);

  // ---- staging geometry (pre-swizzled global source, linear GLDS dest)
  const int rb    = (w << 3) + (l >> 3);              // 0..63
  const int chunk = ((l & 7) ^ (l >> 3)) << 3;        // swizzled k-chunk (elems)
  const u16* pAg = xb  + (size_t)(b0 + rb) * IN_DIM + chunk;
  const u16* pBg = wbt + (size_t)(n0 + rb) * IN_DIM + chunk;

#define STAGE_A(q, bufE, kkv)                                              \
  GLDS16(pAg + (size_t)(q) * 65536 + (kkv) * 64,                           \
         sm + (bufE) + (q) * 4096 + (w << 9))
#define STAGE_B(q, bufE, ev, kkv)                                          \
  GLDS16(pBg + (size_t)(ev) * 1048576 + (size_t)(q) * 65536 + (kkv) * 64,  \
         sm + (bufE) + 16384 + (q) * 4096 + (w << 9))

  // ---- fragment read byte-offsets (within a buffer)
  const int lane15 = l & 15;
  const int swzb = (((l >> 4) << 4)) ^ ((l & 7) << 4);
  const int aoff0 = (wm << 14) + lane15 * 128 + swzb;            // A, kf=0
  const int boff0 = 32768 + (wn << 12) + lane15 * 128 + swzb;    // B, kf=0
  // kf=1 address = kf0 address ^ 64 (kf bit 6 commutes with the XOR mask)

  f32x4 accY[8][2], accE[8][2];
#pragma unroll
  for (int m = 0; m < 8; ++m)
#pragma unroll
    for (int n = 0; n < 2; ++n) {
      accY[m][n] = (f32x4){0.f, 0.f, 0.f, 0.f};
      accE[m][n] = (f32x4){0.f, 0.f, 0.f, 0.f};
    }

  // ---- prologue: stage tiles 0 (buf0) and 1 (buf1); wait tile0 only
  STAGE_A(0, 0, 0); STAGE_A(1, 0, 0); STAGE_A(2, 0, 0); STAGE_A(3, 0, 0);
  STAGE_B(0, 0, 0, 0); STAGE_B(1, 0, 0, 0);
  STAGE_A(0, 24576, 1); STAGE_A(1, 24576, 1); STAGE_A(2, 24576, 1); STAGE_A(3, 24576, 1);
  STAGE_B(0, 24576, 0, 1); STAGE_B(1, 24576, 0, 1);
  asm volatile("s_waitcnt vmcnt(6)" ::: "memory");
  __builtin_amdgcn_s_barrier();

  int cur = 0;
#pragma unroll 1
  for (int e = 0; e < EXPERTS; ++e) {
#pragma unroll 1
    for (int kk = 0; kk < 16; ++kk) {
      const int t  = (e << 4) + kk;
      const int tn = (t + 2) & 127;          // prefetch target (wraps: harmless)
      const int kkn = tn & 15, en = tn >> 4;
      int stg = cur + 2; if (stg >= 3) stg -= 3;
      const int bufSE = stg * 24576;                     // elems
      const char* rb8 = (const char*)sm + cur * 49152;   // bytes

      bf16x8 a[8][2], bfr[2][2];

      // ---- phase 0: read A m0-3 + B n0-1; stage next A; 16 MFMA
#pragma unroll
      for (int m = 0; m < 4; ++m) {
        a[m][0] = *(const bf16x8*)(rb8 + (aoff0 + m * 2048));
        a[m][1] = *(const bf16x8*)(rb8 + ((aoff0 + m * 2048) ^ 64));
      }
#pragma unroll
      for (int n = 0; n < 2; ++n) {
        bfr[n][0] = *(const bf16x8*)(rb8 + (boff0 + n * 2048));
        bfr[n][1] = *(const bf16x8*)(rb8 + ((boff0 + n * 2048) ^ 64));
      }
      STAGE_A(0, bufSE, kkn); STAGE_A(1, bufSE, kkn);
      STAGE_A(2, bufSE, kkn); STAGE_A(3, bufSE, kkn);
      __builtin_amdgcn_s_barrier();
      asm volatile("s_waitcnt lgkmcnt(0)" ::: "memory");
      __builtin_amdgcn_sched_barrier(0);
      __builtin_amdgcn_s_setprio(1);
#pragma unroll
      for (int m = 0; m < 4; ++m)
#pragma unroll
        for (int n = 0; n < 2; ++n) {
          accE[m][n] = MFMA_BF16(a[m][0], bfr[n][0], accE[m][n], 0, 0, 0);
          accE[m][n] = MFMA_BF16(a[m][1], bfr[n][1], accE[m][n], 0, 0, 0);
        }
      __builtin_amdgcn_s_setprio(0);
      __builtin_amdgcn_s_barrier();

      // ---- phase 1: read A m4-7; stage next B; counted vmcnt; 16 MFMA
#pragma unroll
      for (int m = 4; m < 8; ++m) {
        a[m][0] = *(const bf16x8*)(rb8 + (aoff0 + m * 2048));
        a[m][1] = *(const bf16x8*)(rb8 + ((aoff0 + m * 2048) ^ 64));
      }
      STAGE_B(0, bufSE, en, kkn); STAGE_B(1, bufSE, en, kkn);
      asm volatile("s_waitcnt vmcnt(6)" ::: "memory");   // tile t+1 ready; t+2 in flight
      __builtin_amdgcn_s_barrier();
      asm volatile("s_waitcnt lgkmcnt(0)" ::: "memory");
      __builtin_amdgcn_sched_barrier(0);
      __builtin_amdgcn_s_setprio(1);
#pragma unroll
      for (int m = 4; m < 8; ++m)
#pragma unroll
        for (int n = 0; n < 2; ++n) {
          accE[m][n] = MFMA_BF16(a[m][0], bfr[n][0], accE[m][n], 0, 0, 0);
          accE[m][n] = MFMA_BF16(a[m][1], bfr[n][1], accE[m][n], 0, 0, 0);
        }
      __builtin_amdgcn_s_setprio(0);
      __builtin_amdgcn_s_barrier();

      cur++; if (cur == 3) cur = 0;
    }
    // ---- fold expert e: accY += w[b,e] * accE ; accE = 0  (LDS weights)
#pragma unroll
    for (int m = 0; m < 8; ++m) {
      const int wrow = (wm << 7) + (m << 4) + ((l >> 4) << 2);
      const f32x4 wv = *(const f32x4*)(wl + e * 256 + wrow);
#pragma unroll
      for (int n = 0; n < 2; ++n)
#pragma unroll
        for (int j = 0; j < 4; ++j) {
          accY[m][n][j] += wv[j] * accE[m][n][j];
          accE[m][n][j] = 0.f;
        }
    }
  }
  asm volatile("s_waitcnt vmcnt(0)" ::: "memory");   // drain wrap-around stages

  // ---- epilogue: bias term + store fp32
  float bv[2][8];
#pragma unroll
  for (int n = 0; n < 2; ++n) {
    const int c = n0 + (wn << 5) + (n << 4) + lane15;
#pragma unroll
    for (int ee = 0; ee < 8; ++ee) bv[n][ee] = bias[ee * OUT_DIM + c];
  }
#pragma unroll
  for (int m = 0; m < 8; ++m) {
    const int wrow = (wm << 7) + (m << 4) + ((l >> 4) << 2);
    f32x4 wv[8];
#pragma unroll
    for (int ee = 0; ee < 8; ++ee) wv[ee] = *(const f32x4*)(wl + ee * 256 + wrow);
#pragma unroll
    for (int n = 0; n < 2; ++n) {
      const int c = n0 + (wn << 5) + (n << 4) + lane15;
#pragma unroll
      for (int j = 0; j < 4; ++j) {
        float v = accY[m][n][j];
#pragma unroll
        for (int ee = 0; ee < 8; ++ee) v += wv[ee][j] * bv[n][ee];
        y[(size_t)(b0 + wrow + j) * OUT_DIM + c] = v;
      }
    }
  }
}

extern "C" void kernel_launch(void* const* d_in, const int* in_sizes, int n_in,
                              void* d_out, int out_size, void* d_ws, size_t ws_size,
                              hipStream_t stream) {
  const float* x    = (const float*)d_in[0];
  const float* wts  = (const float*)d_in[1];
  const float* W    = (const float*)d_in[2];
  const float* bias = (const float*)d_in[3];
  float* y = (float*)d_out;

  const size_t xb_elems = (size_t)BATCH * IN_DIM;                 // 32 MB bf16
  const size_t wb_elems = (size_t)EXPERTS * IN_DIM * OUT_DIM;     // 16 MB bf16
  if (ws_size < (xb_elems + wb_elems) * sizeof(u16)) return;      // loud failure
  u16* xb  = (u16*)d_ws;
  u16* wbt = xb + xb_elems;

  cvt_x<<<(BATCH * IN_DIM) / (4 * 256), 256, 0, stream>>>(x, xb);
  cvt_w<<<dim3(IN_DIM / 64, OUT_DIM / 64, EXPERTS), 256, 0, stream>>>(W, wbt);
  moe_gemm<<<dim3((BATCH / 256) * (OUT_DIM / 128)), 512, 0, stream>>>(xb, wbt, wts, bias, y);
}

// Round 4
// 321.428 us; speedup vs baseline: 1.0794x; 1.0497x over previous
//
#include <hip/hip_runtime.h>
#include <hip/hip_bf16.h>
#include <stdint.h>

#define BATCH   16384
#define EXPERTS 8
#define IN_DIM  1024
#define OUT_DIM 1024

typedef unsigned short u16;
typedef short  bf16x8 __attribute__((ext_vector_type(8)));
typedef float  f32x4  __attribute__((ext_vector_type(4)));

__device__ __forceinline__ u16 f2bf(float f) {
  uint32_t u = __float_as_uint(f);
  u += 0x7fffu + ((u >> 16) & 1u);   // round-to-nearest-even
  return (u16)(u >> 16);
}

// async global->LDS, 16B per lane, wave-uniform LDS base + lane*16
#define GLDS16(g, l)                                                      \
  __builtin_amdgcn_global_load_lds(                                       \
      (const __attribute__((address_space(1))) void*)(g),                 \
      (__attribute__((address_space(3))) void*)(l), 16, 0, 0)

#define MFMA_BF16 __builtin_amdgcn_mfma_f32_16x16x32_bf16

// ---------------- kernel 1: x fp32 -> bf16 ----------------
__global__ void cvt_x(const float* __restrict__ x, u16* __restrict__ xb) {
  size_t i = ((size_t)blockIdx.x * 256 + threadIdx.x) * 4;
  float4 v = *reinterpret_cast<const float4*>(x + i);
  ushort4 o;
  o.x = f2bf(v.x); o.y = f2bf(v.y); o.z = f2bf(v.z); o.w = f2bf(v.w);
  *reinterpret_cast<ushort4*>(xb + i) = o;
}

// ------- kernel 2: W[e][i][o] fp32 -> Wbt[e][o][i] bf16 (transpose) -------
__global__ void cvt_w(const float* __restrict__ W, u16* __restrict__ wbt) {
  __shared__ u16 t[64][72];            // +8 pad
  const int e  = blockIdx.z;
  const int i0 = blockIdx.x * 64;
  const int o0 = blockIdx.y * 64;
  const int tid = threadIdx.x;
  const int c  = (tid & 15) * 4;
  const int r_ = tid >> 4;
  const float* src = W + ((size_t)e << 20);
#pragma unroll
  for (int p = 0; p < 4; ++p) {
    int r = r_ + p * 16;               // i-row
    float4 v = *reinterpret_cast<const float4*>(src + (size_t)(i0 + r) * 1024 + o0 + c);
    t[r][c + 0] = f2bf(v.x); t[r][c + 1] = f2bf(v.y);
    t[r][c + 2] = f2bf(v.z); t[r][c + 3] = f2bf(v.w);
  }
  __syncthreads();
  u16* dst = wbt + ((size_t)e << 20);
#pragma unroll
  for (int p = 0; p < 4; ++p) {
    int orow = r_ + p * 16;            // o-row
    ushort4 u;
    u.x = t[c + 0][orow]; u.y = t[c + 1][orow];
    u.z = t[c + 2][orow]; u.w = t[c + 3][orow];
    *reinterpret_cast<ushort4*>(dst + (size_t)(o0 + orow) * 1024 + i0 + c) = u;
  }
}

// ---------------- kernel 3: fused expert GEMM, K-tile outer / expert inner
// BM=256 BN=128 BK=64, 512 threads = 8 waves (2M x 4N), wave -> 128x32 out.
// A staged ONCE per K-tile (shared by all 8 experts), a-frags held in regs.
// Per expert-phase: 32 MFMA folded immediately (accY += w[row,e] * t).
// SYNC DISCIPLINE (fixes r3 race): stage -> counted vmcnt (covers all loads
// issued <= g-2) -> barrier -> LDS reads -> lgkmcnt(0) -> MFMA -> barrier.
// Reads drained before end-barrier; overwrites issued only after it.
//
// LDS (u16 elems): A dbuf @0,@16384 (16384 ea); B bufs @32768,@40960,@49152
// (8192 ea); wl f32[8][256] @57344 (4096 elems). Total 61440 elems = 120KB.
__global__ __launch_bounds__(512, 2)
void moe_gemm(const u16* __restrict__ xb, const u16* __restrict__ wbt,
              const float* __restrict__ wts, const float* __restrict__ bias,
              float* __restrict__ y) {
  __shared__ u16 sm[61440];
  const char* smb = (const char*)sm;
  float* wl = (float*)(sm + 57344);

  const int tid = threadIdx.x;
  const int l   = tid & 63;
  const int w   = tid >> 6;            // wave 0..7
  const int wm  = w >> 2;              // 0..1  (M half)
  const int wn  = w & 3;               // 0..3  (N quarter)
  const int n0  = (blockIdx.x & 7) * 128;   // XCD-affine B-panel
  const int b0  = (blockIdx.x >> 3) * 256;

  // ---- stage expert weights wl[e][256] for this block's rows (ds_write)
#pragma unroll
  for (int i = 0; i < 4; ++i) {
    const int flat = tid + i * 512;
    const int ee = flat & 7, r = flat >> 3;
    wl[ee * 256 + r] = wts[(size_t)(b0 + r) * EXPERTS + ee];
  }

  // ---- staging geometry (pre-swizzled global source, linear GLDS dest)
  const int rb    = (w << 3) + (l >> 3);              // 0..63
  const int chunk = ((l & 7) ^ (l >> 3)) << 3;        // swizzled k-chunk (elems)
  const u16* pAg = xb  + (size_t)(b0 + rb) * IN_DIM + chunk;
  const u16* pBg = wbt + (size_t)(n0 + rb) * IN_DIM + chunk;

  // ---- fragment read byte-offsets
  const int lane15 = l & 15;
  const int swzb  = (((l >> 4) << 4)) ^ ((l & 7) << 4);
  const int aoffb = (wm << 14) + lane15 * 128 + swzb;   // within A buf (bytes)
  const int boffb = (wn << 12) + lane15 * 128 + swzb;   // within B buf (bytes)
  const int wlo   = (wm << 9) + ((l >> 4) << 4);        // wl byte offset per m

  f32x4 accY[8][2];
#pragma unroll
  for (int m = 0; m < 8; ++m)
#pragma unroll
    for (int n = 0; n < 2; ++n) accY[m][n] = (f32x4){0.f, 0.f, 0.f, 0.f};
  const f32x4 fz = (f32x4){0.f, 0.f, 0.f, 0.f};

  bf16x8 a[8][2];

  // ---- prologue: A(tile0)x4 -> Abuf0; B(e0) pair -> buf0; B(e1) pair -> buf1
#pragma unroll
  for (int q = 0; q < 4; ++q)
    GLDS16(pAg + (size_t)q * 65536, sm + q * 4096 + (w << 9));
  GLDS16(pBg,                    sm + 32768 + (w << 9));
  GLDS16(pBg + 65536,            sm + 32768 + 4096 + (w << 9));
  GLDS16(pBg + 1048576,          sm + 40960 + (w << 9));
  GLDS16(pBg + 1048576 + 65536,  sm + 40960 + 4096 + (w << 9));
  asm volatile("s_waitcnt lgkmcnt(0)" ::: "memory");  // wl ds_writes drained
  __builtin_amdgcn_s_barrier();

  int arE = 0, awE = 16384;                   // A read/write buf (elems)
  int rb0 = 32768, rb1 = 40960, rb2 = 49152;  // B buf rotation (elems)

// E: expert phase 0..7 (compile-time). VM: literal vmcnt count =
// issues(this phase) + issues(prev phase) -> everything staged <= g-2 done.
#define PHASE(E, VM)                                                       \
  {                                                                        \
    { /* stage B for phase g+2 into rb2 */                                 \
      const int et = ((E) <= 5) ? ((E) + 2) : ((E) - 6);                   \
      const int kt = ((E) <= 5) ? kk : kn;                                 \
      const u16* srcB = pBg + (size_t)et * 1048576 + (size_t)kt * 64;      \
      GLDS16(srcB,         sm + rb2 + (w << 9));                           \
      GLDS16(srcB + 65536, sm + rb2 + 4096 + (w << 9)); }                  \
    if ((E) < 4)  /* stage A part E of tile kn */                          \
      GLDS16(pAg + (size_t)(E) * 65536 + (size_t)kn * 64,                  \
             sm + awE + (E) * 4096 + (w << 9));                            \
    asm volatile("s_waitcnt vmcnt(" #VM ")" ::: "memory");                 \
    __builtin_amdgcn_s_barrier();                                          \
    if ((E) == 0) {  /* fresh a-frags for this K-tile (16 x ds_read_b128) */ \
      _Pragma("unroll")                                                    \
      for (int m = 0; m < 8; ++m) {                                        \
        a[m][0] = *(const bf16x8*)(smb + (arE * 2 + aoffb + m * 2048));    \
        a[m][1] = *(const bf16x8*)(smb + ((arE * 2 + aoffb + m * 2048) ^ 64)); \
      }                                                                    \
    }                                                                      \
    bf16x8 bc[2][2];                                                       \
    _Pragma("unroll")                                                      \
    for (int n = 0; n < 2; ++n) {                                          \
      bc[n][0] = *(const bf16x8*)(smb + (rb0 * 2 + boffb + n * 2048));     \
      bc[n][1] = *(const bf16x8*)(smb + ((rb0 * 2 + boffb + n * 2048) ^ 64)); \
    }                                                                      \
    asm volatile("s_waitcnt lgkmcnt(0)" ::: "memory");                     \
    __builtin_amdgcn_sched_barrier(0);                                     \
    __builtin_amdgcn_s_setprio(1);                                         \
    _Pragma("unroll")                                                      \
    for (int m = 0; m < 8; ++m) {                                          \
      const f32x4 wvm = *(const f32x4*)(smb + 114688 + (E) * 1024 + wlo + m * 64); \
      _Pragma("unroll")                                                    \
      for (int n = 0; n < 2; ++n) {                                        \
        f32x4 t = MFMA_BF16(a[m][0], bc[n][0], fz, 0, 0, 0);               \
        t = MFMA_BF16(a[m][1], bc[n][1], t, 0, 0, 0);                      \
        accY[m][n] += wvm * t;                                             \
      }                                                                    \
    }                                                                      \
    __builtin_amdgcn_s_setprio(0);                                         \
    __builtin_amdgcn_s_barrier();                                          \
    { int _t = rb0; rb0 = rb1; rb1 = rb2; rb2 = _t; }                      \
  }

#pragma unroll 1
  for (int kk = 0; kk < 16; ++kk) {
    const int kn = (kk + 1) & 15;
    PHASE(0, 5)
    PHASE(1, 6)
    PHASE(2, 6)
    PHASE(3, 6)
    PHASE(4, 5)
    PHASE(5, 4)
    PHASE(6, 4)
    PHASE(7, 4)
    { int _t = arE; arE = awE; awE = _t; }
  }
  asm volatile("s_waitcnt vmcnt(0)" ::: "memory");   // drain wrap-around stages

  // ---- epilogue: bias term + store fp32
  float bv[2][8];
#pragma unroll
  for (int n = 0; n < 2; ++n) {
    const int c = n0 + (wn << 5) + (n << 4) + lane15;
#pragma unroll
    for (int ee = 0; ee < 8; ++ee) bv[n][ee] = bias[ee * OUT_DIM + c];
  }
#pragma unroll
  for (int m = 0; m < 8; ++m) {
    const int wrow = (wm << 7) + (m << 4) + ((l >> 4) << 2);
    f32x4 wv[8];
#pragma unroll
    for (int ee = 0; ee < 8; ++ee) wv[ee] = *(const f32x4*)(wl + ee * 256 + wrow);
#pragma unroll
    for (int n = 0; n < 2; ++n) {
      const int c = n0 + (wn << 5) + (n << 4) + lane15;
#pragma unroll
      for (int j = 0; j < 4; ++j) {
        float v = accY[m][n][j];
#pragma unroll
        for (int ee = 0; ee < 8; ++ee) v += wv[ee][j] * bv[n][ee];
        y[(size_t)(b0 + wrow + j) * OUT_DIM + c] = v;
      }
    }
  }
}

extern "C" void kernel_launch(void* const* d_in, const int* in_sizes, int n_in,
                              void* d_out, int out_size, void* d_ws, size_t ws_size,
                              hipStream_t stream) {
  const float* x    = (const float*)d_in[0];
  const float* wts  = (const float*)d_in[1];
  const float* W    = (const float*)d_in[2];
  const float* bias = (const float*)d_in[3];
  float* y = (float*)d_out;

  const size_t xb_elems = (size_t)BATCH * IN_DIM;                 // 32 MB bf16
  const size_t wb_elems = (size_t)EXPERTS * IN_DIM * OUT_DIM;     // 16 MB bf16
  if (ws_size < (xb_elems + wb_elems) * sizeof(u16)) return;      // loud failure
  u16* xb  = (u16*)d_ws;
  u16* wbt = xb + xb_elems;

  cvt_x<<<(BATCH * IN_DIM) / (4 * 256), 256, 0, stream>>>(x, xb);
  cvt_w<<<dim3(IN_DIM / 64, OUT_DIM / 64, EXPERTS), 256, 0, stream>>>(W, wbt);
  moe_gemm<<<dim3((BATCH / 256) * (OUT_DIM / 128)), 512, 0, stream>>>(xb, wbt, wts, bias, y);
}